// Round 18
// baseline (2407.836 us; speedup 1.0000x reference)
//
#include <hip/hip_runtime.h>
#include <hip/hip_fp16.h>
#include <hip/hip_cooperative_groups.h>

namespace cg = cooperative_groups;

#define NA   16384   // n_angles * N
#define NN   2048    // N
#define CIN  16
#define COUT 32
#define NANG 8
#define KCH  15
#define NSTEP  512               // 16384/32 K-steps per wave (full K)
#define CHUNK  4                 // K-steps per pipelined chunk
#define NCHUNK (NSTEP / CHUNK)   // 128
#define NPANEL 1024              // 16-row panels
#define PGRID  ((NN * COUT) / 256)   // 256 proj blocks (fallback path)
#define SGRID  (NPANEL / 4)          // 256 sweep blocks (4 waves each)
#define TGRID  ((8 * 64 * 64) / 256) // 128 tile blocks
#define WSTRIDE (NANG * CIN * COUT)

// T iterates grow to ~3e5 -> fp16 mirror stored pre-scaled by 2^-5 (exact).
#define TSCALE_INV 0.03125f
#define TSCALE     32.0f

// Fragment layouts (linear in global K-step ST for each wave):
//  Lsw flat = p*262144 + ST*512 + l*8 ;  Tsw flat = ST*512 + l*8
// Semantics: lane l (rc=l&15, kg=l>>4), step ST:
//   A = Ls[p*16+rc][ST*32 + kg*8 .. +7],  B = T[rc][ST*32 + kg*8 .. +7]

typedef _Float16 f16x8 __attribute__((ext_vector_type(8)));
typedef _Float16 f16x4 __attribute__((ext_vector_type(4)));
typedef float    f32x4 __attribute__((ext_vector_type(4)));

__device__ __forceinline__ void tile_body(const float* __restrict__ x,
                                          float* __restrict__ T32,
                                          _Float16* __restrict__ Tsw, int bid) {
    int tid = bid * 256 + threadIdx.x;              // 0 .. 32767
    const int s  = tid >> 12;
    const int st = (tid >> 6) & 63;
    const int l  = tid & 63;
    const int ch = l & 15;
    const int c2 = ((l >> 4) << 3) + (st << 5);
    f16x8 h;
    float v[8];
    #pragma unroll
    for (int e = 0; e < 8; ++e) {
        v[e] = x[(c2 + e) * CIN + ch];
        h[e] = (_Float16)(v[e] * TSCALE_INV);
    }
    float* d = T32 + (size_t)ch * NA + s * (NA / 8) + c2;
    *(float4*)(d)     = make_float4(v[0], v[1], v[2], v[3]);
    *(float4*)(d + 4) = make_float4(v[4], v[5], v[6], v[7]);
    *(f16x8*)(Tsw + (size_t)tid * 8) = h;
}

__device__ __forceinline__ void proj_body(const float* __restrict__ Tt,
                                          const float* __restrict__ W,
                                          const float* __restrict__ bias,
                                          float* __restrict__ out, int add,
                                          int idx) {
    const int n  = idx >> 5;
    const int co = idx & 31;
    float s = add ? out[idx] : bias[co];
    #pragma unroll
    for (int a = 0; a < NANG; ++a)
        #pragma unroll
        for (int ci = 0; ci < CIN; ++ci)
            s = fmaf(Tt[(size_t)ci * NA + a * NN + n],
                     W[(size_t)(a * CIN + ci) * COUT + co], s);
    out[idx] = s;
}

// NTST: 1 = nontemporal Lsw store (multi-launch path, kernel-end flush);
//       0 = normal store (coop path - must be visible through grid.sync()).
#define LOADCHUNK(BUF, PC, NTST)                                             \
    _Pragma("unroll")                                                        \
    for (int u = 0; u < CHUNK; ++u) {                                        \
        const int st = (PC) * CHUNK + u;                                     \
        if (CONV) {                                                          \
            f32x4 f0 = __builtin_nontemporal_load((const f32x4*)(aF + (size_t)st * 32));     \
            f32x4 f1 = __builtin_nontemporal_load((const f32x4*)(aF + (size_t)st * 32 + 4)); \
            f16x8 h;                                                         \
            h[0] = (_Float16)f0[0]; h[1] = (_Float16)f0[1];                  \
            h[2] = (_Float16)f0[2]; h[3] = (_Float16)f0[3];                  \
            h[4] = (_Float16)f1[0]; h[5] = (_Float16)f1[1];                  \
            h[6] = (_Float16)f1[2]; h[7] = (_Float16)f1[3];                  \
            if (NTST) { __builtin_nontemporal_store(h, (f16x8*)(aW + (size_t)st * 512)); }   \
            else      { *(f16x8*)(aW + (size_t)st * 512) = h; }              \
            A[BUF][u] = h;                                                   \
        } else {                                                             \
            A[BUF][u] = __builtin_nontemporal_load((const f16x8*)(aP + (size_t)st * 512));   \
        }                                                                    \
        B[BUF][u] = *(const f16x8*)(bP + (size_t)st * 512);                  \
    }

template<int CONV, int NTST>
__device__ __forceinline__ void sweep_body(const float* __restrict__ Ls,
                                           _Float16* __restrict__ Lsw,
                                           const _Float16* __restrict__ Tsw,
                                           const float* __restrict__ Tp,
                                           float* __restrict__ Tn,
                                           _Float16* __restrict__ Tswn,
                                           float alpha, float beta, int bid) {
    constexpr int DEPTH = CONV ? 2 : 4;
    static_assert(NCHUNK % 2 == 0 && NCHUNK % 4 == 0,
                  "tail chunk would replay stale buffer");
    const int w  = threadIdx.x >> 6;
    const int l  = threadIdx.x & 63;
    const int p  = bid * 4 + w;                     // panel 0..1023
    const int rc = l & 15;
    const int kg = l >> 4;

    const size_t aoff = (size_t)p * (NSTEP * 512) + (size_t)l * 8;
    const _Float16* aP = Lsw + aoff;
    _Float16*       aW = Lsw + aoff;
    const float*    aF = Ls + (size_t)(p * 16 + rc) * NA + kg * 8;
    const _Float16* bP = Tsw + (size_t)l * 8;

    f32x4 acc = {0.f, 0.f, 0.f, 0.f};
    f16x8 A[DEPTH][CHUNK], B[DEPTH][CHUNK];

    LOADCHUNK(0, 0, NTST);
    if (DEPTH >= 3) { LOADCHUNK(1 & (DEPTH - 1), 1, NTST); }
    if (DEPTH >= 4) { LOADCHUNK(2 & (DEPTH - 1), 2, NTST); }

    #pragma unroll 1
    for (int cc = 0; cc < NCHUNK; cc += DEPTH) {
        #pragma unroll
        for (int d = 0; d < DEPTH; ++d) {
            const int pf = cc + d + DEPTH - 1;
            if (pf < NCHUNK) { LOADCHUNK((d + DEPTH - 1) % DEPTH, pf, NTST); }
            #pragma unroll
            for (int u = 0; u < CHUNK; ++u)
                acc = __builtin_amdgcn_mfma_f32_16x16x32_f16(A[d][u], B[d][u],
                                                             acc, 0, 0, 0);
        }
    }

    // Epilogue: lane l covers ch=rc, positions p*16 + kg*4 + i (i=0..3)
    const size_t tb = (size_t)rc * NA + (size_t)p * 16 + kg * 4;
    float4 tp4 = make_float4(0.f, 0.f, 0.f, 0.f);
    if (beta != 0.f) tp4 = *(const float4*)(Tp + tb);
    const float v0 = alpha * acc[0] + beta * tp4.x;
    const float v1 = alpha * acc[1] + beta * tp4.y;
    const float v2 = alpha * acc[2] + beta * tp4.z;
    const float v3 = alpha * acc[3] + beta * tp4.w;
    *(float4*)(Tn + tb) = make_float4(v0, v1, v2, v3);
    const int c0 = p * 16 + kg * 4;
    const size_t tf = ((size_t)(c0 >> 5) * 64 + ((c0 >> 3) & 3) * 16 + rc) * 8
                      + (c0 & 7);
    f16x4 h;
    h[0] = (_Float16)(v0 * TSCALE_INV); h[1] = (_Float16)(v1 * TSCALE_INV);
    h[2] = (_Float16)(v2 * TSCALE_INV); h[3] = (_Float16)(v3 * TSCALE_INV);
    *(f16x4*)(Tswn + tf) = h;
}

// ---------- cooperative single-launch path: 256 blocks (1/CU guaranteed) ----
// Each block: (tile if b<128) / per-phase: proj_{k-1} (tiny) then sweep_k.
__global__ __launch_bounds__(256)
void k_fused(const float* __restrict__ x, const float* __restrict__ Ls,
             const float* __restrict__ W, const float* __restrict__ bias,
             float* __restrict__ out, _Float16* __restrict__ Lsw,
             float* __restrict__ T32b, _Float16* __restrict__ Tswb) {
    const size_t TSZ = (size_t)CIN * NA;
    float*    T32[3] = { T32b, T32b + TSZ, T32b + 2 * TSZ };
    _Float16* Tsw[3] = { Tswb, Tswb + TSZ, Tswb + 2 * TSZ };
    cg::grid_group grid = cg::this_grid();
    const int b   = (int)blockIdx.x;                // 0..255
    const int idx = b * 256 + (int)threadIdx.x;     // proj index (65536 total)

    if (b < TGRID) tile_body(x, T32[0], Tsw[0], b);
    grid.sync();

    // k=1: proj_0 (init out from bias) then CONV sweep (normal Lsw stores)
    proj_body(T32[0], W, bias, out, 0, idx);
    sweep_body<1, 0>(Ls, Lsw, Tsw[0], T32[0], T32[1], Tsw[1], TSCALE, 0.f, b);
    grid.sync();

    #pragma unroll 1
    for (int k = 2; k < KCH; ++k) {
        const int cur = (k - 1) % 3, prev = (k - 2) % 3, nxt = k % 3;
        proj_body(T32[cur], W + (size_t)(k - 1) * WSTRIDE, bias, out, 1, idx);
        const int bid = (k & 1) ? b : (SGRID - 1 - b);   // ping-pong
        sweep_body<0, 0>(Ls, Lsw, Tsw[cur], T32[prev], T32[nxt], Tsw[nxt],
                         2.0f * TSCALE, -1.f, bid);
        grid.sync();
    }

    proj_body(T32[(KCH - 1) % 3], W + (size_t)(KCH - 1) * WSTRIDE,
              bias, out, 1, idx);
}

// ---------- fallback: exact round-16 multi-launch path (verified 1687us) ----
__global__ __launch_bounds__(256) void k_tile_t(const float* __restrict__ x,
                                                float* __restrict__ T32,
                                                _Float16* __restrict__ Tsw) {
    tile_body(x, T32, Tsw, (int)blockIdx.x);
}

template<int CONV, int REV>
__global__ __launch_bounds__(256)
void k_sweep(const float* __restrict__ Ls, _Float16* __restrict__ Lsw,
             const _Float16* __restrict__ Tsw, const float* __restrict__ Tp,
             float* __restrict__ Tn, _Float16* __restrict__ Tswn,
             float alpha, float beta,
             const float* __restrict__ Tproj, const float* __restrict__ Wk,
             const float* __restrict__ bias, float* __restrict__ out, int add) {
    if (blockIdx.x < PGRID) {
        proj_body(Tproj, Wk, bias, out, add,
                  (int)blockIdx.x * 256 + (int)threadIdx.x);
        return;
    }
    const int bid0 = (int)blockIdx.x - PGRID;
    const int bid  = REV ? (SGRID - 1 - bid0) : bid0;
    sweep_body<CONV, 1>(Ls, Lsw, Tsw, Tp, Tn, Tswn, alpha, beta, bid);
}

__global__ __launch_bounds__(256) void k_proj_t(const float* __restrict__ Tt,
                                                const float* __restrict__ W,
                                                const float* __restrict__ bias,
                                                float* __restrict__ out, int add) {
    proj_body(Tt, W, bias, out, add, (int)blockIdx.x * 256 + (int)threadIdx.x);
}

extern "C" void kernel_launch(void* const* d_in, const int* in_sizes, int n_in,
                              void* d_out, int out_size, void* d_ws, size_t ws_size,
                              hipStream_t stream) {
    const float* x    = (const float*)d_in[0];
    const float* Ls   = (const float*)d_in[1];
    const float* W    = (const float*)d_in[2];
    const float* bias = (const float*)d_in[3];
    float* out = (float*)d_out;

    char* wsb = (char*)d_ws;
    _Float16* Lsw = (_Float16*)wsb;                                   // 512 MiB
    float* T32b = (float*)(wsb + (size_t)NA * NA * sizeof(_Float16));
    const size_t TSZ = (size_t)CIN * NA;
    float* T32[3] = { T32b, T32b + TSZ, T32b + 2 * TSZ };
    _Float16* Tswb = (_Float16*)(T32b + 3 * TSZ);
    _Float16* Tsw[3] = { Tswb, Tswb + TSZ, Tswb + 2 * TSZ };

    // coop gate: attribute + conservative grid (256 = 1 block/CU)
    int coop = 0;
    int dev = 0;
    hipGetDevice(&dev);
    hipDeviceGetAttribute(&coop, hipDeviceAttributeCooperativeLaunch, dev);

    hipError_t err = hipErrorUnknown;
    if (coop) {
        const float* xa = x; const float* La = Ls; const float* Wa = W;
        const float* ba = bias; float* oa = out;
        _Float16* lswa = Lsw; float* t32a = T32b; _Float16* tswa = Tswb;
        void* args[] = { (void*)&xa, (void*)&La, (void*)&Wa, (void*)&ba,
                         (void*)&oa, (void*)&lswa, (void*)&t32a, (void*)&tswa };
        err = hipLaunchCooperativeKernel((const void*)k_fused,
                                         dim3(SGRID), dim3(256), args, 0, stream);
    }
    if (err == hipSuccess) return;

    // ---- fallback: round-16 verified multi-launch path ----
    const int GRID = PGRID + SGRID;
    k_tile_t<<<TGRID, 256, 0, stream>>>(x, T32[0], Tsw[0]);
    k_sweep<1, 0><<<GRID, 256, 0, stream>>>(Ls, Lsw, Tsw[0], T32[0],
                                            T32[1], Tsw[1], TSCALE, 0.f,
                                            T32[0], W, bias, out, 0);
    int prev = 0, cur = 1;
    for (int k = 2; k < KCH; ++k) {
        int nxt = 3 - cur - prev;
        const float* Wk = W + (size_t)(k - 1) * WSTRIDE;
        if (k & 1)
            k_sweep<0, 0><<<GRID, 256, 0, stream>>>(Ls, Lsw, Tsw[cur], T32[prev],
                                                    T32[nxt], Tsw[nxt],
                                                    2.0f * TSCALE, -1.f,
                                                    T32[cur], Wk, bias, out, 1);
        else
            k_sweep<0, 1><<<GRID, 256, 0, stream>>>(Ls, Lsw, Tsw[cur], T32[prev],
                                                    T32[nxt], Tsw[nxt],
                                                    2.0f * TSCALE, -1.f,
                                                    T32[cur], Wk, bias, out, 1);
        prev = cur; cur = nxt;
    }
    k_proj_t<<<PGRID, 256, 0, stream>>>(T32[cur], W + (size_t)(KCH - 1) * WSTRIDE,
                                        bias, out, 1);
}

// Round 19
// 1685.681 us; speedup vs baseline: 1.4284x; 1.4284x over previous
//
#include <hip/hip_runtime.h>
#include <hip/hip_fp16.h>

#define NA   16384   // n_angles * N
#define NN   2048    // N
#define CIN  16
#define COUT 32
#define NANG 8
#define KCH  15
#define NSTEP  512               // 16384/32 K-steps per wave (full K)
#define CHUNK  4                 // K-steps per pipelined chunk
#define NCHUNK (NSTEP / CHUNK)   // 128
#define NPANEL 1024              // 16-row panels
#define PGRID  ((NN * COUT) / 256)   // 256 proj blocks
#define SGRID  (NPANEL / 4)          // 256 sweep blocks (4 waves each)

// T iterates grow to ~3e5 -> fp16 mirror stored pre-scaled by 2^-5 (exact).
#define TSCALE_INV 0.03125f
#define TSCALE     32.0f

// Fragment layouts (linear in global K-step ST for each wave):
//  Lsw flat = p*262144 + ST*512 + l*8
//  Tsw flat =            ST*512 + l*8
// Semantics: lane l (rc=l&15, kg=l>>4), step ST:
//   A = Ls[p*16+rc][ST*32 + kg*8 .. +7],  B = T[rc][ST*32 + kg*8 .. +7]

typedef _Float16 f16x8 __attribute__((ext_vector_type(8)));
typedef _Float16 f16x4 __attribute__((ext_vector_type(4)));
typedef float    f32x4 __attribute__((ext_vector_type(4)));

// Build T0: f32 master [CIN][NA] + fragment-layout scaled fp16 mirror.
__global__ __launch_bounds__(256) void k_tile_t(const float* __restrict__ x,
                                                float* __restrict__ T32,
                                                _Float16* __restrict__ Tsw) {
    int tid = blockIdx.x * 256 + threadIdx.x;       // 0 .. 32767
    if (tid >= 8 * 64 * 64) return;
    const int s  = tid >> 12;
    const int st = (tid >> 6) & 63;
    const int l  = tid & 63;
    const int ch = l & 15;
    const int c2 = ((l >> 4) << 3) + (st << 5);     // in-slice col base
    f16x8 h;
    float v[8];
    #pragma unroll
    for (int e = 0; e < 8; ++e) {
        v[e] = x[(c2 + e) * CIN + ch];
        h[e] = (_Float16)(v[e] * TSCALE_INV);
    }
    float* d = T32 + (size_t)ch * NA + s * (NA / 8) + c2;
    *(float4*)(d)     = make_float4(v[0], v[1], v[2], v[3]);
    *(float4*)(d + 4) = make_float4(v[4], v[5], v[6], v[7]);
    *(f16x8*)(Tsw + (size_t)tid * 8) = h;
}

__device__ __forceinline__ void proj_body(const float* __restrict__ Tt,
                                          const float* __restrict__ W,
                                          const float* __restrict__ bias,
                                          float* __restrict__ out, int add,
                                          int idx) {
    const int n  = idx >> 5;
    const int co = idx & 31;
    float s = add ? out[idx] : bias[co];
    #pragma unroll
    for (int a = 0; a < NANG; ++a)
        #pragma unroll
        for (int ci = 0; ci < CIN; ++ci)
            s = fmaf(Tt[(size_t)ci * NA + a * NN + n],
                     W[(size_t)(a * CIN + ci) * COUT + co], s);
    out[idx] = s;
}

// Fused sweep (round-14 verified structure: NT A-stream everywhere) PLUS
// proj piggyback: the first PGRID blocks project T_{k-1} (read-only overlap
// with the sweep's inputs - no conflict with the buffers sweep_k writes),
// removing 14 serialized tiny proj launches from the critical path.
// CONV=1: A from fp32 Ls (nt), converted + written (nt) to Lsw.
// REV=1: reverse sweep-block order (L3 ping-pong across sweeps).
#define LOADCHUNK(BUF, PC)                                                   \
    _Pragma("unroll")                                                        \
    for (int u = 0; u < CHUNK; ++u) {                                        \
        const int st = (PC) * CHUNK + u;                                     \
        if (CONV) {                                                          \
            f32x4 f0 = __builtin_nontemporal_load((const f32x4*)(aF + (size_t)st * 32));     \
            f32x4 f1 = __builtin_nontemporal_load((const f32x4*)(aF + (size_t)st * 32 + 4)); \
            f16x8 h;                                                         \
            h[0] = (_Float16)f0[0]; h[1] = (_Float16)f0[1];                  \
            h[2] = (_Float16)f0[2]; h[3] = (_Float16)f0[3];                  \
            h[4] = (_Float16)f1[0]; h[5] = (_Float16)f1[1];                  \
            h[6] = (_Float16)f1[2]; h[7] = (_Float16)f1[3];                  \
            __builtin_nontemporal_store(h, (f16x8*)(aW + (size_t)st * 512)); \
            A[BUF][u] = h;                                                   \
        } else {                                                             \
            A[BUF][u] = __builtin_nontemporal_load((const f16x8*)(aP + (size_t)st * 512));   \
        }                                                                    \
        B[BUF][u] = *(const f16x8*)(bP + (size_t)st * 512);                  \
    }

template<int CONV, int REV>
__global__ __launch_bounds__(256)
void k_sweep(const float* __restrict__ Ls,
             _Float16* __restrict__ Lsw,
             const _Float16* __restrict__ Tsw,     // T_{k-1} fp16 scaled (B)
             const float* __restrict__ Tp,         // T_{k-2} f32 (beta term)
             float* __restrict__ Tn,               // T_k f32 master out
             _Float16* __restrict__ Tswn,          // T_k fp16 mirror out
             float alpha, float beta,
             const float* __restrict__ Tproj,      // T_{k-1} f32 (proj input)
             const float* __restrict__ Wk,         // weight[k-1]
             const float* __restrict__ bias,
             float* __restrict__ out, int add) {
    // ---- piggyback proj blocks (first PGRID blocks) ----
    if (blockIdx.x < PGRID) {
        proj_body(Tproj, Wk, bias, out, add,
                  (int)blockIdx.x * 256 + (int)threadIdx.x);
        return;
    }
    // ---- sweep blocks ----
    constexpr int DEPTH = CONV ? 2 : 4;             // chunks in flight
    static_assert(NCHUNK % 2 == 0 && NCHUNK % 4 == 0,
                  "tail chunk would replay stale buffer");
    const int w    = threadIdx.x >> 6;
    const int l    = threadIdx.x & 63;
    const int bid0 = (int)blockIdx.x - PGRID;
    const int bid  = REV ? (SGRID - 1 - bid0) : bid0;
    const int p    = bid * 4 + w;                   // panel 0..1023
    const int rc   = l & 15;
    const int kg   = l >> 4;

    const size_t aoff = (size_t)p * (NSTEP * 512) + (size_t)l * 8;
    const _Float16* aP = Lsw + aoff;
    _Float16*       aW = Lsw + aoff;
    const float*    aF = Ls + (size_t)(p * 16 + rc) * NA + kg * 8;
    const _Float16* bP = Tsw + (size_t)l * 8;

    f32x4 acc = {0.f, 0.f, 0.f, 0.f};
    f16x8 A[DEPTH][CHUNK], B[DEPTH][CHUNK];

    // prologue: prefetch DEPTH-1 chunks
    LOADCHUNK(0, 0);
    if (DEPTH >= 3) { LOADCHUNK(1 & (DEPTH - 1), 1); }
    if (DEPTH >= 4) { LOADCHUNK(2 & (DEPTH - 1), 2); }

    #pragma unroll 1
    for (int cc = 0; cc < NCHUNK; cc += DEPTH) {
        #pragma unroll
        for (int d = 0; d < DEPTH; ++d) {           // compute chunk cc+d (buf d)
            const int pf = cc + d + DEPTH - 1;      // prefetch distance DEPTH-1
            if (pf < NCHUNK) { LOADCHUNK((d + DEPTH - 1) % DEPTH, pf); }
            #pragma unroll
            for (int u = 0; u < CHUNK; ++u)
                acc = __builtin_amdgcn_mfma_f32_16x16x32_f16(A[d][u], B[d][u],
                                                             acc, 0, 0, 0);
        }
    }

    // Epilogue: lane l covers ch=rc, positions p*16 + kg*4 + i (i=0..3)
    const size_t tb = (size_t)rc * NA + (size_t)p * 16 + kg * 4;
    float4 tp4 = make_float4(0.f, 0.f, 0.f, 0.f);
    if (beta != 0.f) tp4 = *(const float4*)(Tp + tb);
    const float v0 = alpha * acc[0] + beta * tp4.x;
    const float v1 = alpha * acc[1] + beta * tp4.y;
    const float v2 = alpha * acc[2] + beta * tp4.z;
    const float v3 = alpha * acc[3] + beta * tp4.w;
    *(float4*)(Tn + tb) = make_float4(v0, v1, v2, v3);
    // fp16 mirror in fragment layout: 4 consecutive halves at
    // flat = ((c0>>5)*64 + ((c0>>3)&3)*16 + rc)*8 + (c0&7), c0 = p*16+kg*4
    const int c0 = p * 16 + kg * 4;
    const size_t tf = ((size_t)(c0 >> 5) * 64 + ((c0 >> 3) & 3) * 16 + rc) * 8
                      + (c0 & 7);
    f16x4 h;
    h[0] = (_Float16)(v0 * TSCALE_INV); h[1] = (_Float16)(v1 * TSCALE_INV);
    h[2] = (_Float16)(v2 * TSCALE_INV); h[3] = (_Float16)(v3 * TSCALE_INV);
    *(f16x4*)(Tswn + tf) = h;
}

// standalone proj (only for the final k=14 projection)
__global__ __launch_bounds__(256) void k_proj_t(const float* __restrict__ Tt,
                                                const float* __restrict__ W,
                                                const float* __restrict__ bias,
                                                float* __restrict__ out, int add) {
    int idx = blockIdx.x * 256 + threadIdx.x;
    if (idx >= NN * COUT) return;
    proj_body(Tt, W, bias, out, add, idx);
}

extern "C" void kernel_launch(void* const* d_in, const int* in_sizes, int n_in,
                              void* d_out, int out_size, void* d_ws, size_t ws_size,
                              hipStream_t stream) {
    const float* x    = (const float*)d_in[0];
    const float* Ls   = (const float*)d_in[1];
    const float* W    = (const float*)d_in[2];
    const float* bias = (const float*)d_in[3];
    float* out = (float*)d_out;

    char* wsb = (char*)d_ws;
    _Float16* Lsw = (_Float16*)wsb;                                   // 512 MiB
    float* T32base = (float*)(wsb + (size_t)NA * NA * sizeof(_Float16));
    const size_t TSZ = (size_t)CIN * NA;
    float* T32[3] = { T32base, T32base + TSZ, T32base + 2 * TSZ };
    _Float16* Tswbase = (_Float16*)(T32base + 3 * TSZ);
    _Float16* Tsw[3] = { Tswbase, Tswbase + TSZ, Tswbase + 2 * TSZ };

    const int WSTRIDE = (NANG * CIN) * COUT;
    const int FGRID = (8 * 64 * 64) / 256;          // 128 blocks
    const int GRID  = PGRID + SGRID;                // 512 blocks

    // T0
    k_tile_t<<<FGRID, 256, 0, stream>>>(x, T32[0], Tsw[0]);

    // k = 1 : T1 = Ls @ T0 (alpha=32 unscales fp16 T); converts Ls -> Lsw.
    // Piggyback: proj_0 (T32[0], W[0], add=0 - initializes out with bias).
    k_sweep<1, 0><<<GRID, 256, 0, stream>>>(Ls, Lsw, Tsw[0], T32[0],
                                            T32[1], Tsw[1], TSCALE, 0.f,
                                            T32[0], W, bias, out, 0);

    // k = 2..14 : T2 = 2*(Ls @ T1) - T0 ; piggyback proj_{k-1} on T32[cur]
    int prev = 0, cur = 1;
    for (int k = 2; k < KCH; ++k) {
        int nxt = 3 - cur - prev;
        const float* Wk = W + (size_t)(k - 1) * WSTRIDE;
        if (k & 1)
            k_sweep<0, 0><<<GRID, 256, 0, stream>>>(Ls, Lsw, Tsw[cur], T32[prev],
                                                    T32[nxt], Tsw[nxt],
                                                    2.0f * TSCALE, -1.f,
                                                    T32[cur], Wk, bias, out, 1);
        else
            k_sweep<0, 1><<<GRID, 256, 0, stream>>>(Ls, Lsw, Tsw[cur], T32[prev],
                                                    T32[nxt], Tsw[nxt],
                                                    2.0f * TSCALE, -1.f,
                                                    T32[cur], Wk, bias, out, 1);
        prev = cur; cur = nxt;
    }

    // final projection of T14
    k_proj_t<<<PGRID, 256, 0, stream>>>(T32[cur], W + (size_t)(KCH - 1) * WSTRIDE,
                                        bias, out, 1);
}